// Round 2
// baseline (2631.425 us; speedup 1.0000x reference)
//
#include <hip/hip_runtime.h>
#include <cstdint>

#define NN 50000
#define EE 800000
#define GG 64

typedef unsigned short u16;
typedef __attribute__((ext_vector_type(8))) short bf16x8;
typedef __attribute__((ext_vector_type(4))) float f32x4;

__device__ __forceinline__ float bf2f(u16 v) { return __uint_as_float(((unsigned)v) << 16); }
__device__ __forceinline__ u16 f2bf(float f) {
  unsigned u = __float_as_uint(f);
  return (u16)((u + 0x7fffu + ((u >> 16) & 1u)) >> 16);
}

// Direct addrspacecast (generic->AS1 / generic->AS3) — no int truncation.
__device__ __forceinline__ void gload_lds16(const void* g, void* l) {
  __builtin_amdgcn_global_load_lds(
      (const __attribute__((address_space(1))) void*)g,
      (__attribute__((address_space(3))) void*)l,
      16, 0, 0);
}

__global__ void k_sentinel(float* out) { out[threadIdx.x] = 1e12f; }

// ---------------- encoder: hb = bf16(relu(x @ enc_W + b)) --------------------
__global__ __launch_bounds__(256) void k_encoder(
    const float* __restrict__ x, const float* __restrict__ W,
    const float* __restrict__ b, u16* __restrict__ hb) {
  int idx = blockIdx.x * 256 + threadIdx.x;
  if (idx >= NN * 256) return;
  int row = idx >> 8, j = idx & 255;
  float s = b[j];
#pragma unroll
  for (int k = 0; k < 6; ++k) s += x[row * 6 + k] * W[k * 256 + j];
  hb[idx] = f2bf(fmaxf(s, 0.f));
}

// ---------------- graph size features ----------------------------------------
__global__ __launch_bounds__(256) void k_count_nodes(const int* __restrict__ batch,
                                                     int* __restrict__ ncnt) {
  int i = blockIdx.x * 256 + threadIdx.x;
  if (i < NN) atomicAdd(&ncnt[batch[i]], 1);
}

__global__ __launch_bounds__(256) void k_count_edges(const int* __restrict__ src,
                                                     const int* __restrict__ batch,
                                                     int* __restrict__ ecnt) {
  __shared__ int loc[GG];
  if (threadIdx.x < GG) loc[threadIdx.x] = 0;
  __syncthreads();
  int i = blockIdx.x * 256 + threadIdx.x;
  if (i < EE) atomicAdd(&loc[batch[src[i]]], 1);
  __syncthreads();
  if (threadIdx.x < GG) {
    int v = loc[threadIdx.x];
    if (v) atomicAdd(&ecnt[threadIdx.x], v);
  }
}

__global__ void k_log_feats(const int* __restrict__ ncnt, const int* __restrict__ ecnt,
                            float* __restrict__ gf) {
  int g = threadIdx.x;
  if (g < GG) {
    gf[g * 2] = logf((float)ncnt[g] + 1.f);
    gf[g * 2 + 1] = logf((float)ecnt[g] + 1.f);
  }
}

// ---------------- router (fp32 end-to-end, 8 nodes/block) --------------------
__global__ __launch_bounds__(256) void k_router(
    const float* __restrict__ x, const float* __restrict__ encW, const float* __restrict__ encb,
    const int* __restrict__ batch, const float* __restrict__ gf,
    const float* __restrict__ W1, const float* __restrict__ b1,
    const float* __restrict__ W2, const float* __restrict__ b2,
    float* __restrict__ sparse) {
  __shared__ float hs[8][256];
  __shared__ float rs[8][256];
  __shared__ float xv[8][6];
  __shared__ float sf[8][2];
  __shared__ float lg[8][8];
  int tid = threadIdx.x;
  int nb = blockIdx.x * 8;
  if (tid < 48) {
    int r = tid / 6, k = tid % 6;
    int node = nb + r;
    xv[r][k] = (node < NN) ? x[node * 6 + k] : 0.f;
  }
  if (tid >= 48 && tid < 56) {
    int r = tid - 48;
    int node = nb + r;
    int g = (node < NN) ? batch[node] : 0;
    sf[r][0] = gf[g * 2];
    sf[r][1] = gf[g * 2 + 1];
  }
  __syncthreads();
  // h in fp32 (exact same arithmetic as reference encoder)
  {
    float wcol[6];
#pragma unroll
    for (int k = 0; k < 6; ++k) wcol[k] = encW[k * 256 + tid];
    float bb = encb[tid];
#pragma unroll
    for (int r = 0; r < 8; ++r) {
      float s = bb;
#pragma unroll
      for (int k = 0; k < 6; ++k) s += xv[r][k] * wcol[k];
      hs[r][tid] = fmaxf(s, 0.f);
    }
  }
  __syncthreads();
  float acc[8];
  float bb = b1[tid];
#pragma unroll
  for (int r = 0; r < 8; ++r) acc[r] = bb;
  for (int k = 0; k < 256; ++k) {
    float w = W1[k * 256 + tid];
#pragma unroll
    for (int r = 0; r < 8; ++r) acc[r] += hs[r][k] * w;
  }
  {
    float w0 = W1[256 * 256 + tid], w1v = W1[257 * 256 + tid];
#pragma unroll
    for (int r = 0; r < 8; ++r) acc[r] += sf[r][0] * w0 + sf[r][1] * w1v;
  }
#pragma unroll
  for (int r = 0; r < 8; ++r) rs[r][tid] = fmaxf(acc[r], 0.f);
  __syncthreads();
  if (tid < 64) {
    int r = tid >> 3, e = tid & 7;
    float s = b2[e];
    for (int k = 0; k < 256; ++k) s += rs[r][k] * W2[k * 8 + e];
    lg[r][e] = s;
  }
  __syncthreads();
  if (tid < 8) {
    int node = nb + tid;
    if (node < NN) {
      float v1 = lg[tid][0];
      int j1 = 0;
#pragma unroll
      for (int j = 1; j < 8; ++j) {
        float v = lg[tid][j];
        if (v > v1) { v1 = v; j1 = j; }
      }
      float v2 = -1e30f;
      int j2 = 0;
#pragma unroll
      for (int j = 0; j < 8; ++j) {
        if (j == j1) continue;
        float v = lg[tid][j];
        if (v > v2) { v2 = v; j2 = j; }
      }
      float ex = expf(v2 - v1);
      float wa = 1.f / (1.f + ex), wb = ex / (1.f + ex);
      float* sp = sparse + node * 8;
#pragma unroll
      for (int j = 0; j < 8; ++j) sp[j] = 0.f;
      sp[j1] = wa;
      sp[j2] = wb;
    }
  }
}

// ---------------- CSR build (by dst) -----------------------------------------
__global__ __launch_bounds__(256) void k_deg(const int* __restrict__ dst, int* __restrict__ deg) {
  int i = blockIdx.x * 256 + threadIdx.x;
  if (i < EE) atomicAdd(&deg[dst[i]], 1);
}

__global__ __launch_bounds__(1024) void k_scan(const int* __restrict__ deg,
                                               int* __restrict__ rowptr) {
  __shared__ int tmp[1024];
  __shared__ int carry;
  if (threadIdx.x == 0) { carry = 0; rowptr[0] = 0; }
  __syncthreads();
  for (int base = 0; base < NN; base += 1024) {
    int i = base + threadIdx.x;
    int v = (i < NN) ? deg[i] : 0;
    tmp[threadIdx.x] = v;
    __syncthreads();
    for (int off = 1; off < 1024; off <<= 1) {
      int t = (threadIdx.x >= off) ? tmp[threadIdx.x - off] : 0;
      __syncthreads();
      tmp[threadIdx.x] += t;
      __syncthreads();
    }
    if (i < NN) rowptr[i + 1] = carry + tmp[threadIdx.x];
    int last = tmp[1023];
    __syncthreads();
    if (threadIdx.x == 0) carry += last;
    __syncthreads();
  }
}

__global__ __launch_bounds__(256) void k_fill(const int* __restrict__ ei,
                                              const int* __restrict__ rowptr,
                                              int* __restrict__ cursor, int* __restrict__ csrc) {
  int i = blockIdx.x * 256 + threadIdx.x;
  if (i < EE) {
    int s = ei[i], d = ei[EE + i];
    int pos = atomicAdd(&cursor[d], 1);
    csrc[rowptr[d] + pos] = s;
  }
}

// ---------------- SpMM: Y[d] = sum_{e: dst=d} X[src[e]]  (bf16 in/out) -------
__global__ __launch_bounds__(256) void k_spmm256(
    const int* __restrict__ rowptr, const int* __restrict__ csrc,
    const u16* __restrict__ X, u16* __restrict__ Y) {
  int wave = threadIdx.x >> 6, lane = threadIdx.x & 63;
  int d = blockIdx.x * 4 + wave;
  if (d >= NN) return;
  int s0 = rowptr[d], s1 = rowptr[d + 1];
  int c4 = lane * 4;
  float a0 = 0.f, a1 = 0.f, a2 = 0.f, a3 = 0.f;
  int i = s0;
  for (; i + 2 <= s1; i += 2) {
    int sa = csrc[i], sb = csrc[i + 1];
    ushort4 va = *(const ushort4*)(X + sa * 256 + c4);
    ushort4 vb = *(const ushort4*)(X + sb * 256 + c4);
    a0 += bf2f(va.x) + bf2f(vb.x);
    a1 += bf2f(va.y) + bf2f(vb.y);
    a2 += bf2f(va.z) + bf2f(vb.z);
    a3 += bf2f(va.w) + bf2f(vb.w);
  }
  if (i < s1) {
    int sa = csrc[i];
    ushort4 va = *(const ushort4*)(X + sa * 256 + c4);
    a0 += bf2f(va.x);
    a1 += bf2f(va.y);
    a2 += bf2f(va.z);
    a3 += bf2f(va.w);
  }
  ushort4 o;
  o.x = f2bf(a0); o.y = f2bf(a1); o.z = f2bf(a2); o.w = f2bf(a3);
  *(ushort4*)(Y + d * 256 + c4) = o;
}

// ---------------- weight transpose+bf16: W[m][k][j] -> Wt[m][j][k] -----------
__global__ __launch_bounds__(256) void k_transpose(const float* __restrict__ W,
                                                   u16* __restrict__ Wt, int nmat) {
  int idx = blockIdx.x * 256 + threadIdx.x;
  if (idx >= nmat * 65536) return;
  int m = idx >> 16, rem = idx & 65535;
  int k = rem >> 8, j = rem & 255;
  Wt[(m << 16) + (j << 8) + k] = f2bf(W[idx]);
}

// ---------------- fused dual-source MFMA GEMM --------------------------------
// Y[m,0:256] = act( X1[m,:]@W1t^T + X2[m,:]@W2t^T + bias )
// Tile 128x256, 8 waves (64x64 each), BK=32, 16x16x32 bf16 MFMA.
// In-place safe (Y==X1): A-tile reads only the block's own rows.
__global__ __launch_bounds__(512) void k_gemm(
    const u16* __restrict__ X1, const u16* __restrict__ X2,
    const u16* __restrict__ W1t, const u16* __restrict__ W2t,
    const float* __restrict__ bias, u16* __restrict__ Y, int relu) {
  __shared__ __align__(16) u16 Alds[128 * 32];  // 8KB
  __shared__ __align__(16) u16 Blds[256 * 32];  // 16KB
  int tid = threadIdx.x;
  int wave = tid >> 6, lane = tid & 63;
  int l15 = lane & 15, l4 = lane >> 4;
  int m0 = blockIdx.x * 128;
  int wr = wave >> 2, wc = wave & 3;
  const f32x4 fz = {0.f, 0.f, 0.f, 0.f};
  f32x4 acc[4][4];
#pragma unroll
  for (int a = 0; a < 4; ++a)
#pragma unroll
    for (int b = 0; b < 4; ++b) acc[a][b] = fz;

  for (int kt = 0; kt < 16; ++kt) {
    const u16* xs = (kt < 8) ? X1 : X2;
    const u16* wsrc = (kt < 8) ? W1t : W2t;
    int kb = (kt & 7) * 32;
    __syncthreads();  // previous tile's LDS reads done
    {
      int flat = wave * 1024 + lane * 16;  // byte position in Alds
      int row = flat >> 6, colb = flat & 63;
      int gr = m0 + row;
      if (gr > NN - 1) gr = NN - 1;  // clamp (finite garbage; masked on write)
      gload_lds16(xs + gr * 256 + kb + (colb >> 1), (char*)Alds + wave * 1024);
    }
#pragma unroll
    for (int q = 0; q < 2; ++q) {
      int flat = q * 8192 + wave * 1024 + lane * 16;
      int row = flat >> 6, colb = flat & 63;
      gload_lds16(wsrc + row * 256 + kb + (colb >> 1), (char*)Blds + q * 8192 + wave * 1024);
    }
    __syncthreads();  // barrier drains vmcnt -> staging visible
    bf16x8 af[4], bfv[4];
#pragma unroll
    for (int mi = 0; mi < 4; ++mi) {
      int r = wr * 64 + mi * 16 + l15;
      af[mi] = *(const bf16x8*)(Alds + r * 32 + l4 * 8);
    }
#pragma unroll
    for (int nj = 0; nj < 4; ++nj) {
      int c = wc * 64 + nj * 16 + l15;
      bfv[nj] = *(const bf16x8*)(Blds + c * 32 + l4 * 8);
    }
#pragma unroll
    for (int mi = 0; mi < 4; ++mi)
#pragma unroll
      for (int nj = 0; nj < 4; ++nj)
        acc[mi][nj] =
            __builtin_amdgcn_mfma_f32_16x16x32_bf16(af[mi], bfv[nj], acc[mi][nj], 0, 0, 0);
  }
  // epilogue: C/D map col=lane&15, row=(lane>>4)*4+reg  [m89-verified]
#pragma unroll
  for (int mi = 0; mi < 4; ++mi) {
    int rbase = m0 + wr * 64 + mi * 16 + l4 * 4;
#pragma unroll
    for (int nj = 0; nj < 4; ++nj) {
      int col = wc * 64 + nj * 16 + l15;
      float bv = bias[col];
#pragma unroll
      for (int r2 = 0; r2 < 4; ++r2) {
        int row = rbase + r2;
        if (row < NN) {
          float v = acc[mi][nj][r2] + bv;
          if (relu) v = fmaxf(v, 0.f);
          Y[row * 256 + col] = f2bf(v);
        }
      }
    }
  }
}

// ---------------- output projection: Y4[n] = [he@Wr (2), he@Wn (2)] ----------
__global__ __launch_bounds__(256) void k_outproj(
    const u16* __restrict__ he, const float* __restrict__ Wr,
    const float* __restrict__ Wn, float* __restrict__ Y4) {
  __shared__ float Ws[256 * 4];
  int tid = threadIdx.x;
  Ws[tid * 4 + 0] = Wr[tid * 2];
  Ws[tid * 4 + 1] = Wr[tid * 2 + 1];
  Ws[tid * 4 + 2] = Wn[tid * 2];
  Ws[tid * 4 + 3] = Wn[tid * 2 + 1];
  __syncthreads();
  int wave = tid >> 6, lane = tid & 63;
  int node = blockIdx.x * 4 + wave;
  if (node >= NN) return;
  const u16* hrow = he + node * 256;
  int k0 = lane * 4;
  ushort4 hv4 = *(const ushort4*)(hrow + k0);
  float hv[4] = {bf2f(hv4.x), bf2f(hv4.y), bf2f(hv4.z), bf2f(hv4.w)};
  float a0 = 0.f, a1 = 0.f, a2 = 0.f, a3 = 0.f;
#pragma unroll
  for (int t = 0; t < 4; ++t) {
    float hvv = hv[t];
    const float* w = Ws + (k0 + t) * 4;
    a0 += hvv * w[0];
    a1 += hvv * w[1];
    a2 += hvv * w[2];
    a3 += hvv * w[3];
  }
#pragma unroll
  for (int off = 32; off > 0; off >>= 1) {
    a0 += __shfl_down(a0, off);
    a1 += __shfl_down(a1, off);
    a2 += __shfl_down(a2, off);
    a3 += __shfl_down(a3, off);
  }
  if (lane == 0) {
    float* y = Y4 + node * 4;
    y[0] = a0; y[1] = a1; y[2] = a2; y[3] = a3;
  }
}

// out[d] += sparse[d,e] * (Y4[d,0:2] + sum_in-edges Y4[src,2:4] + b)
__global__ __launch_bounds__(256) void k_out_combine(
    const int* __restrict__ rowptr, const int* __restrict__ csrc,
    const float* __restrict__ Y4, const float* __restrict__ sparse,
    const float* __restrict__ ob, float* __restrict__ out, int e) {
  int d = blockIdx.x * 256 + threadIdx.x;
  if (d >= NN) return;
  float a0 = 0.f, a1 = 0.f;
  for (int i = rowptr[d]; i < rowptr[d + 1]; ++i) {
    int s = csrc[i];
    a0 += Y4[s * 4 + 2];
    a1 += Y4[s * 4 + 3];
  }
  float w = sparse[d * 8 + e];
  out[d * 2] += w * (Y4[d * 4] + a0 + ob[0]);
  out[d * 2 + 1] += w * (Y4[d * 4 + 1] + a1 + ob[1]);
}

extern "C" void kernel_launch(void* const* d_in, const int* in_sizes, int n_in,
                              void* d_out, int out_size, void* d_ws, size_t ws_size,
                              hipStream_t stream) {
  const float* x = (const float*)d_in[0];
  const int* ei = (const int*)d_in[1];
  const int* batch = (const int*)d_in[2];
  const float* enc_W = (const float*)d_in[3];
  const float* enc_b = (const float*)d_in[4];
  const float* rW1 = (const float*)d_in[5];
  const float* rb1 = (const float*)d_in[6];
  const float* rW2 = (const float*)d_in[7];
  const float* rb2 = (const float*)d_in[8];
  const float* hid_Wr = (const float*)d_in[9];
  const float* hid_Wn = (const float*)d_in[10];
  const float* hid_b = (const float*)d_in[11];
  const float* out_Wr = (const float*)d_in[12];
  const float* out_Wn = (const float*)d_in[13];
  const float* out_b = (const float*)d_in[14];
  float* out = (float*)d_out;

  char* ws = (char*)d_ws;
  size_t off = 0;
  auto alloc = [&](size_t bytes) -> void* {
    void* p = ws + off;
    off = (off + bytes + 511) & ~(size_t)511;
    return p;
  };
  u16* hb = (u16*)alloc((size_t)NN * 256 * 2);     // 25.6 MB
  u16* agg0 = (u16*)alloc((size_t)NN * 256 * 2);   // 25.6 MB
  u16* he = (u16*)alloc((size_t)NN * 256 * 2);     // 25.6 MB
  u16* agg = (u16*)alloc((size_t)NN * 256 * 2);    // 25.6 MB
  u16* WrT = (u16*)alloc((size_t)24 * 65536 * 2);  // 3.15 MB
  u16* WnT = (u16*)alloc((size_t)24 * 65536 * 2);  // 3.15 MB
  int* deg = (int*)alloc((size_t)NN * 4);
  int* rowptr = (int*)alloc((size_t)(NN + 1) * 4);
  int* cursor = (int*)alloc((size_t)NN * 4);
  int* csrc = (int*)alloc((size_t)EE * 4);  // 3.2 MB
  int* ncnt = (int*)alloc(GG * 4);
  int* ecnt = (int*)alloc(GG * 4);
  float* gf = (float*)alloc(GG * 2 * 4);
  float* sparse = (float*)alloc((size_t)NN * 8 * 4);  // 1.6 MB
  float* Y4 = (float*)alloc((size_t)NN * 4 * 4);      // 0.8 MB
  // total ~116 MB
  if (off > ws_size) {  // workspace too small -> unambiguous sentinel, no OOB
    k_sentinel<<<1, 2, 0, stream>>>(out);
    return;
  }

  hipMemsetAsync(deg, 0, (size_t)NN * 4, stream);
  hipMemsetAsync(cursor, 0, (size_t)NN * 4, stream);
  hipMemsetAsync(ncnt, 0, GG * 4, stream);
  hipMemsetAsync(ecnt, 0, GG * 4, stream);
  hipMemsetAsync(out, 0, (size_t)NN * 2 * 4, stream);

  k_encoder<<<(NN * 256 + 255) / 256, 256, 0, stream>>>(x, enc_W, enc_b, hb);
  k_transpose<<<(24 * 65536 + 255) / 256, 256, 0, stream>>>(hid_Wr, WrT, 24);
  k_transpose<<<(24 * 65536 + 255) / 256, 256, 0, stream>>>(hid_Wn, WnT, 24);
  k_count_nodes<<<(NN + 255) / 256, 256, 0, stream>>>(batch, ncnt);
  k_count_edges<<<(EE + 255) / 256, 256, 0, stream>>>(ei, batch, ecnt);
  k_log_feats<<<1, 64, 0, stream>>>(ncnt, ecnt, gf);
  k_router<<<NN / 8, 256, 0, stream>>>(x, enc_W, enc_b, batch, gf, rW1, rb1, rW2, rb2, sparse);
  k_deg<<<(EE + 255) / 256, 256, 0, stream>>>(ei + EE, deg);
  k_scan<<<1, 1024, 0, stream>>>(deg, rowptr);
  k_fill<<<(EE + 255) / 256, 256, 0, stream>>>(ei, rowptr, cursor, csrc);

  const int gemm_grid = (NN + 127) / 128;
  // shared layer-0 aggregation of h (identical input for every expert)
  k_spmm256<<<(NN + 3) / 4, 256, 0, stream>>>(rowptr, csrc, hb, agg0);
  for (int e = 0; e < 8; ++e) {
    k_gemm<<<gemm_grid, 512, 0, stream>>>(hb, agg0, WrT + e * 65536, WnT + e * 65536,
                                          hid_b + e * 256, he, 1);
    for (int l = 1; l < 3; ++l) {
      k_spmm256<<<(NN + 3) / 4, 256, 0, stream>>>(rowptr, csrc, he, agg);
      k_gemm<<<gemm_grid, 512, 0, stream>>>(he, agg, WrT + (l * 8 + e) * 65536,
                                            WnT + (l * 8 + e) * 65536,
                                            hid_b + (l * 8 + e) * 256, he, 1);
    }
    // output layer: project first (H->4), aggregate the tiny vectors (linearity)
    k_outproj<<<(NN + 3) / 4, 256, 0, stream>>>(he, out_Wr + e * 512, out_Wn + e * 512, Y4);
    k_out_combine<<<(NN + 255) / 256, 256, 0, stream>>>(rowptr, csrc, Y4, sparse,
                                                        out_b + e * 2, out, e);
  }
}